// Round 2
// baseline (2536.903 us; speedup 1.0000x reference)
//
#include <hip/hip_runtime.h>

typedef unsigned int u32;
typedef unsigned long long u64;
typedef float f32x2 __attribute__((ext_vector_type(2)));

#define NPB 8192
#define BCL 4
#define MS 2048
#define KN 64
#define NTH 512                               // fps threads: 8 waves, 16 pts/thread
#define OFF_POS   (BCL * MS * 128)            // element offsets into d_out (f32)
#define OFF_BATCH (OFF_POS + BCL * MS * 3)

__device__ inline u64 umax64(u64 a, u64 b) { return a < b ? b : a; }
__device__ inline u32 umax32(u32 a, u32 b) { return a < b ? b : a; }

// packed f32 ops: IEEE-identical per half to v_add_f32 / v_mul_f32 -> bit-exact
__device__ inline f32x2 pk_add(f32x2 a, f32x2 b) {
  f32x2 d;
  asm("v_pk_add_f32 %0, %1, %2" : "=v"(d) : "v"(a), "v"(b));
  return d;
}
__device__ inline f32x2 pk_mul(f32x2 a, f32x2 b) {
  f32x2 d;
  asm("v_pk_mul_f32 %0, %1, %2" : "=v"(d) : "v"(a), "v"(b));
  return d;
}

// wave64 max via DPP (VALU forwarding, no LDS round-trips).
__device__ inline u32 wave_max_u32(u32 v) {
  v = umax32(v, (u32)__builtin_amdgcn_update_dpp(0, (int)v, 0x111, 0xf, 0xf, false));
  v = umax32(v, (u32)__builtin_amdgcn_update_dpp(0, (int)v, 0x112, 0xf, 0xf, false));
  v = umax32(v, (u32)__builtin_amdgcn_update_dpp(0, (int)v, 0x114, 0xf, 0xf, false));
  v = umax32(v, (u32)__builtin_amdgcn_update_dpp(0, (int)v, 0x118, 0xf, 0xf, false));
  v = umax32(v, (u32)__builtin_amdgcn_update_dpp(0, (int)v, 0x142, 0xa, 0xf, false));
  v = umax32(v, (u32)__builtin_amdgcn_update_dpp(0, (int)v, 0x143, 0xc, 0xf, false));
  return (u32)__builtin_amdgcn_readlane((int)v, 63);
}
// two-phase DPP reduce == lexicographic u64 max over the wave (tie -> min idx)
__device__ inline u64 wave_max_key(u64 lkey) {
  u32 hi = (u32)(lkey >> 32), lo32v = (u32)lkey;
  u32 m = wave_max_u32(hi);
  u32 c = wave_max_u32(hi == m ? lo32v : 0u);
  return ((u64)m << 32) | c;
}

__device__ inline u32 part1by2(u32 x) {   // spread 10 bits -> every 3rd bit
  x &= 0x3ffu;
  x = (x | (x << 16)) & 0x030000FFu;
  x = (x | (x << 8))  & 0x0300F00Fu;
  x = (x | (x << 4))  & 0x030C30C3u;
  x = (x | (x << 2))  & 0x09249249u;
  return x;
}

// ---------------------------------------------------------------------------
// Kernel 1: FPS. R9 = R8 (LDS coord table, bbox prune, DPP argmax, single-slot
// atomicMax combine) with HALF the waves: 512 threads x 16 pts/thread, kept as
// TWO independent 8-pt Morton-contiguous blobs per thread, each with its own
// bbox + its own running key half. Pruning granularity therefore unchanged
// (still per-8-pt bbox); per-point arithmetic op-for-op identical; max is
// associative -> bit-exact (absmax 0.0 expected). What halves: the serialized
// same-address atomicMax chain (16->8 posts/iter), barrier participants
// (16->8 waves), and per-SIMD skip-path issue contention (4->2 waves/SIMD).
// Key = d2bits<<32 | ~origidx -> np.argmax tie semantics.
// ---------------------------------------------------------------------------
__global__ __launch_bounds__(NTH) void fps_kernel(
    const float* __restrict__ pos, int* __restrict__ samp,
    float* __restrict__ out) {
  // [0,128K): float4 tab[8192]  (overlaps u64 sortb[8192] in [0,64K) -- sortb
  //           dead before tab is written)
  // [128K, 128K+24): u64 slot[3] triple-buffered atomicMax slots
  // [128K+32, 128K+32+8K): int s_samp[2048]
  __shared__ __align__(16) unsigned char smem_raw[NPB * 16 + 32 + MS * 4];
  u64* sortb = (u64*)smem_raw;
  float4* tab = (float4*)smem_raw;
  u64* slot = (u64*)(smem_raw + NPB * 16);
  int* s_samp = (int*)(smem_raw + NPB * 16 + 32);

  int b = blockIdx.x, t = threadIdx.x, lane = t & 63;
  const float* pb = pos + (size_t)b * NPB * 3;

  // ---- 1) Morton keys (30b) | orig idx (13b) ----
  for (int i = t; i < NPB; i += NTH) {
    float xx = pb[i * 3], yy = pb[i * 3 + 1], zz = pb[i * 3 + 2];
    u32 xi = (u32)fminf(fmaxf(xx * 1024.0f, 0.0f), 1023.0f);
    u32 yi = (u32)fminf(fmaxf(yy * 1024.0f, 0.0f), 1023.0f);
    u32 zi = (u32)fminf(fmaxf(zz * 1024.0f, 0.0f), 1023.0f);
    u32 m = (part1by2(zi) << 2) | (part1by2(yi) << 1) | part1by2(xi);
    sortb[i] = ((u64)m << 13) | (u32)i;
  }
  // ---- 2) bitonic sort 8192 (LDS-throughput bound, not wave-count bound) ----
  for (int k = 2; k <= NPB; k <<= 1) {
    for (int j = k >> 1; j > 0; j >>= 1) {
      __syncthreads();
      for (int i = t; i < NPB; i += NTH) {
        int ix = i ^ j;
        if (ix > i) {
          u64 a = sortb[i], c = sortb[ix];
          bool up = ((i & k) == 0);
          if ((a > c) == up) { sortb[i] = c; sortb[ix] = a; }
        }
      }
    }
  }
  __syncthreads();
  // ---- 3) extract my 16-pt blob (Morton-contiguous, two 8-pt halves) ----
  int oi[16];
  #pragma unroll
  for (int i = 0; i < 16; ++i) oi[i] = (int)(sortb[16 * t + i] & 0x1FFFu);
  __syncthreads();                 // sort buffer dead; tab may overwrite it

  // ---- 3.5) fill LDS coordinate table (coalesced) + init slots ----
  for (int i = t; i < NPB; i += NTH) {
    float xx = pb[i * 3], yy = pb[i * 3 + 1], zz = pb[i * 3 + 2];
    tab[i] = float4{xx, yy, zz, 0.0f};
  }
  if (t < 3) slot[t] = 0;
  if (t == 0) s_samp[0] = 0;
  __syncthreads();                 // tab complete + slots zeroed

  // ---- 4) gather coords from tab + per-half bbox + tie-break lo words ----
  f32x2 px[8], py[8], pz[8], mind[8];
  u32 lo[16];
  float bxl[2], bxh[2], byl[2], byh[2], bzl[2], bzh[2];
  #pragma unroll
  for (int h = 0; h < 2; ++h) {
    bxl[h] = 1e30f; bxh[h] = -1e30f;
    byl[h] = 1e30f; byh[h] = -1e30f;
    bzl[h] = 1e30f; bzh[h] = -1e30f;
  }
  #pragma unroll
  for (int g = 0; g < 8; ++g) {
    const int h = g >> 2;
    int iA = oi[2 * g], iB = oi[2 * g + 1];
    float4 A = tab[iA], B = tab[iB];
    px[g] = f32x2{A.x, B.x}; py[g] = f32x2{A.y, B.y}; pz[g] = f32x2{A.z, B.z};
    lo[2 * g] = ~(u32)iA; lo[2 * g + 1] = ~(u32)iB;
    bxl[h] = fminf(bxl[h], fminf(A.x, B.x)); bxh[h] = fmaxf(bxh[h], fmaxf(A.x, B.x));
    byl[h] = fminf(byl[h], fminf(A.y, B.y)); byh[h] = fmaxf(byh[h], fmaxf(A.y, B.y));
    bzl[h] = fminf(bzl[h], fminf(A.z, B.z)); bzh[h] = fmaxf(bzh[h], fmaxf(A.z, B.z));
  }
  u64 lkeyh[2];
  u64 wkey;
  {
    float4 c0 = tab[0];
    f32x2 mcx = f32x2{-c0.x, -c0.x}, mcy = f32x2{-c0.y, -c0.y}, mcz = f32x2{-c0.z, -c0.z};
    #pragma unroll
    for (int h = 0; h < 2; ++h) {
      u64 lk = 0;
      #pragma unroll
      for (int j = 0; j < 4; ++j) {
        const int g = 4 * h + j;
        f32x2 dx = pk_add(px[g], mcx), dy = pk_add(py[g], mcy), dz = pk_add(pz[g], mcz);
        mind[g] = pk_add(pk_add(pk_mul(dx, dx), pk_mul(dy, dy)), pk_mul(dz, dz));
        u64 kA = ((u64)__float_as_uint(mind[g].x) << 32) | lo[2 * g];
        u64 kB = ((u64)__float_as_uint(mind[g].y) << 32) | lo[2 * g + 1];
        lk = umax64(lk, umax64(kA, kB));
      }
      lkeyh[h] = lk;
    }
    wkey = wave_max_key(umax64(lkeyh[0], lkeyh[1]));
  }

  // ---- 5) sequential loop: ONE barrier/iter, R5-proven slot rotation ----
  int cur = 0, nxt = 1;
  for (int it = 1; it < MS; ++it) {
    if (lane == 0) atomicMax((u64*)&slot[cur], wkey);
    if (t == 0) slot[nxt] = 0;     // zeroes cur_{it+1}; 2 barriers before reuse
    __syncthreads();
    u64 g = slot[cur];             // broadcast read (same addr, no conflict)
    int win = (int)(~(u32)g) & (NPB - 1);
    if (t == 0) s_samp[it] = win;
    // winner coords: ONE ds_read_b128, same-address broadcast (conflict-free)
    float4 wc = tab[win];
    float ncx = wc.x, ncy = wc.y, ncz = wc.z;
    // conservative per-half bbox skip (bit-exact: only skips provable no-ops)
    bool updh[2];
    #pragma unroll
    for (int h = 0; h < 2; ++h) {
      float lmax = __uint_as_float((u32)(lkeyh[h] >> 32));
      float ax = fmaxf(fmaxf(__fsub_rn(bxl[h], ncx), __fsub_rn(ncx, bxh[h])), 0.0f);
      float ay = fmaxf(fmaxf(__fsub_rn(byl[h], ncy), __fsub_rn(ncy, byh[h])), 0.0f);
      float az = fmaxf(fmaxf(__fsub_rn(bzl[h], ncz), __fsub_rn(ncz, bzh[h])), 0.0f);
      float lb2 = (ax * ax + ay * ay + az * az) * 0.9999961853f;  // *(1-2^-18)
      updh[h] = (lb2 <= lmax);
    }
    if (__ballot(updh[0] | updh[1])) {   // wave-uniform branch
      f32x2 mcx = f32x2{-ncx, -ncx}, mcy = f32x2{-ncy, -ncy}, mcz = f32x2{-ncz, -ncz};
      #pragma unroll
      for (int h = 0; h < 2; ++h) {
        if (updh[h]) {
          u64 acc = 0;
          #pragma unroll
          for (int j = 0; j < 4; ++j) {
            const int g = 4 * h + j;
            f32x2 dx = pk_add(px[g], mcx), dy = pk_add(py[g], mcy), dz = pk_add(pz[g], mcz);
            f32x2 d2 = pk_add(pk_add(pk_mul(dx, dx), pk_mul(dy, dy)), pk_mul(dz, dz));
            mind[g].x = fminf(mind[g].x, d2.x);
            mind[g].y = fminf(mind[g].y, d2.y);
            u64 kA = ((u64)__float_as_uint(mind[g].x) << 32) | lo[2 * g];
            u64 kB = ((u64)__float_as_uint(mind[g].y) << 32) | lo[2 * g + 1];
            acc = umax64(acc, umax64(kA, kB));
          }
          lkeyh[h] = acc;
        }
      }
      wkey = wave_max_key(umax64(lkeyh[0], lkeyh[1]));   // all lanes (DPP)
    }
    cur = nxt;
    nxt = nxt + 1 == 3 ? 0 : nxt + 1;
  }
  __syncthreads();
  // ---- 6) writeback (coords from LDS table) ----
  float* pos_out = out + OFF_POS + (size_t)b * MS * 3;
  float* batch_out = out + OFF_BATCH + (size_t)b * MS;
  for (int m = t; m < MS; m += NTH) {
    int s = s_samp[m];
    samp[b * MS + m] = s;
    float4 c = tab[s];
    pos_out[m * 3] = c.x;
    pos_out[m * 3 + 1] = c.y;
    pos_out[m * 3 + 2] = c.z;
    batch_out[m] = (float)b;
  }
}

// ---------------------------------------------------------------------------
// Kernel 2: radius ball + K-nearest-in-ball (lax.top_k semantics). FROZEN.
// ---------------------------------------------------------------------------
__global__ __launch_bounds__(256) void nbr_kernel(
    const float* __restrict__ pos, const int* __restrict__ samp,
    int* __restrict__ nbr) {
  const float R2CUT = (float)(0.2 * 0.2);   // 0x3D23D70A
  int c = blockIdx.x, b = c >> 11, t = threadIdx.x;
  const float* pb = pos + (size_t)b * NPB * 3;
  int s = samp[c] & (NPB - 1);
  float cx = pb[s * 3], cy = pb[s * 3 + 1], cz = pb[s * 3 + 2];
  __shared__ u64 cand[512];
  __shared__ int cnt;
  if (t == 0) cnt = 0;
  __syncthreads();
  for (int j = t; j < NPB; j += 256) {
    float dx = __fsub_rn(pb[j * 3], cx);
    float dy = __fsub_rn(pb[j * 3 + 1], cy);
    float dz = __fsub_rn(pb[j * 3 + 2], cz);
    float d2 = __fadd_rn(__fadd_rn(__fmul_rn(dx, dx), __fmul_rn(dy, dy)), __fmul_rn(dz, dz));
    if (d2 <= R2CUT) {
      int sl = atomicAdd(&cnt, 1);
      if (sl < 512) cand[sl] = ((u64)__float_as_uint(d2) << 32) | (u32)j;
    }
  }
  __syncthreads();
  int n = cnt; if (n > 512) n = 512;
  for (int i = t; i < 512; i += 256) if (i >= n) cand[i] = ~0ull;
  __syncthreads();
  for (int k = 2; k <= 512; k <<= 1) {
    for (int j = k >> 1; j > 0; j >>= 1) {
      for (int i = t; i < 512; i += 256) {
        int ix = i ^ j;
        if (ix > i) {
          u64 a = cand[i], bb = cand[ix];
          bool up = ((i & k) == 0);
          if ((a > bb) == up) { cand[i] = bb; cand[ix] = a; }
        }
      }
      __syncthreads();
    }
  }
  if (t < KN) nbr[(size_t)c * KN + t] = (t < n) ? (int)(cand[t] & 0xffffffffu) : -1;
}

// ---------------------------------------------------------------------------
// Kernel 3: gather -> f32 VALU MLP -> masked max-pool. FROZEN (absmax 0.0).
// ---------------------------------------------------------------------------
__global__ __launch_bounds__(256) void mlp_kernel(
    const float* __restrict__ x, const float* __restrict__ pos,
    const int* __restrict__ samp, const int* __restrict__ nbr,
    const float* __restrict__ W1, const float* __restrict__ b1,
    const float* __restrict__ W2, const float* __restrict__ b2,
    const float* __restrict__ W3, const float* __restrict__ b3,
    float* __restrict__ out) {
  int c = blockIdx.x, b = c >> 11, t = threadIdx.x;

  __shared__ float s_feat[64][68];
  __shared__ float s_h[64][68];
  __shared__ float s_w[68][64];
  __shared__ float s_mask[64];
  __shared__ float s_red[4][64];

  const int* nb = nbr + (size_t)c * KN;

  {
    int r = t >> 2, q = t & 3;
    int j = nb[r];
    bool valid = (j >= 0 && j < NPB);
    size_t jj = valid ? (size_t)j : 0;
    const float4* xp = (const float4*)(x + ((size_t)b * NPB + jj) * 64 + q * 16);
    float4 v[4];
    for (int i = 0; i < 4; ++i) v[i] = xp[i];
    for (int i = 0; i < 4; ++i) {
      s_feat[r][q * 16 + i * 4 + 0] = valid ? v[i].x : 0.0f;
      s_feat[r][q * 16 + i * 4 + 1] = valid ? v[i].y : 0.0f;
      s_feat[r][q * 16 + i * 4 + 2] = valid ? v[i].z : 0.0f;
      s_feat[r][q * 16 + i * 4 + 3] = valid ? v[i].w : 0.0f;
    }
  }
  if (t < 64) {
    int r = t;
    int j = nb[r];
    bool valid = (j >= 0 && j < NPB);
    s_mask[r] = valid ? 0.0f : -__builtin_inff();
    int s = samp[c] & (NPB - 1);
    size_t jj = valid ? (size_t)j : (size_t)s;
    for (int d = 0; d < 3; ++d) {
      float pj = pos[((size_t)b * NPB + jj) * 3 + d];
      float pc = pos[((size_t)b * NPB + s) * 3 + d];
      s_feat[r][64 + d] = __fsub_rn(pj, pc);
    }
  }
  for (int idx = t; idx < 67 * 64; idx += 256)
    s_w[idx >> 6][idx & 63] = W1[idx];
  __syncthreads();

  {
    int r = t >> 2, n0 = (t & 3) * 16;
    float acc[16];
    for (int j = 0; j < 16; ++j) acc[j] = b1[n0 + j];
    for (int k = 0; k < 67; ++k) {
      float f = s_feat[r][k];
      for (int j = 0; j < 16; ++j) acc[j] += f * s_w[k][n0 + j];
    }
    __syncthreads();
    for (int j = 0; j < 16; ++j) s_h[r][n0 + j] = fmaxf(acc[j], 0.0f);
  }
  for (int idx = t; idx < 64 * 64; idx += 256)
    s_w[idx >> 6][idx & 63] = W2[idx];
  __syncthreads();

  {
    int r = t >> 2, n0 = (t & 3) * 16;
    float acc[16];
    for (int j = 0; j < 16; ++j) acc[j] = b2[n0 + j];
    for (int k = 0; k < 64; ++k) {
      float f = s_h[r][k];
      for (int j = 0; j < 16; ++j) acc[j] += f * s_w[k][n0 + j];
    }
    __syncthreads();
    for (int j = 0; j < 16; ++j) s_feat[r][n0 + j] = fmaxf(acc[j], 0.0f);
  }
  __syncthreads();

  for (int h = 0; h < 2; ++h) {
    for (int idx = t; idx < 64 * 64; idx += 256)
      s_w[idx >> 6][idx & 63] = W3[(size_t)(idx >> 6) * 128 + h * 64 + (idx & 63)];
    __syncthreads();
    int n = t & 63, rg = t >> 6;
    float acc[16];
    float bias = b3[h * 64 + n];
    for (int rr = 0; rr < 16; ++rr) acc[rr] = bias;
    for (int k = 0; k < 64; ++k) {
      float w = s_w[k][n];
      for (int rr = 0; rr < 16; ++rr) acc[rr] += s_feat[rg * 16 + rr][k] * w;
    }
    float m = -__builtin_inff();
    for (int rr = 0; rr < 16; ++rr)
      m = fmaxf(m, fmaxf(acc[rr], 0.0f) + s_mask[rg * 16 + rr]);
    s_red[rg][n] = m;
    __syncthreads();
    if (t < 64) {
      float mm = fmaxf(fmaxf(s_red[0][t], s_red[1][t]), fmaxf(s_red[2][t], s_red[3][t]));
      out[(size_t)c * 128 + h * 64 + t] = mm;
    }
    __syncthreads();
  }
}

// ---------------------------------------------------------------------------
extern "C" void kernel_launch(void* const* d_in, const int* in_sizes, int n_in,
                              void* d_out, int out_size, void* d_ws, size_t ws_size,
                              hipStream_t stream) {
  const float* x   = (const float*)d_in[0];
  const float* pos = (const float*)d_in[1];
  // d_in[2] = batch (int32), unused
  const float* W1 = (const float*)d_in[3];
  const float* b1 = (const float*)d_in[4];
  const float* W2 = (const float*)d_in[5];
  const float* b2 = (const float*)d_in[6];
  const float* W3 = (const float*)d_in[7];
  const float* b3 = (const float*)d_in[8];

  float* out = (float*)d_out;
  int* samp = (int*)d_ws;            // [8192]
  int* nbr = samp + BCL * MS;        // [8192*64]

  fps_kernel<<<BCL, NTH, 0, stream>>>(pos, samp, out);
  nbr_kernel<<<BCL * MS, 256, 0, stream>>>(pos, samp, nbr);
  mlp_kernel<<<BCL * MS, 256, 0, stream>>>(x, pos, samp, nbr,
                                           W1, b1, W2, b2, W3, b3, out);
}

// Round 3
// 2163.014 us; speedup vs baseline: 1.1729x; 1.1729x over previous
//
#include <hip/hip_runtime.h>

typedef unsigned int u32;
typedef unsigned long long u64;
typedef float f32x2 __attribute__((ext_vector_type(2)));

#define NPB 8192
#define BCL 4
#define MS 2048
#define KN 64
#define OFF_POS   (BCL * MS * 128)            // element offsets into d_out (f32)
#define OFF_BATCH (OFF_POS + BCL * MS * 3)

__device__ inline u64 umax64(u64 a, u64 b) { return a < b ? b : a; }
__device__ inline u32 umax32(u32 a, u32 b) { return a < b ? b : a; }

// packed f32 ops: IEEE-identical per half to v_add_f32 / v_mul_f32 -> bit-exact
__device__ inline f32x2 pk_add(f32x2 a, f32x2 b) {
  f32x2 d;
  asm("v_pk_add_f32 %0, %1, %2" : "=v"(d) : "v"(a), "v"(b));
  return d;
}
__device__ inline f32x2 pk_mul(f32x2 a, f32x2 b) {
  f32x2 d;
  asm("v_pk_mul_f32 %0, %1, %2" : "=v"(d) : "v"(a), "v"(b));
  return d;
}

// wave64 max via DPP (VALU forwarding, no LDS round-trips).
__device__ inline u32 wave_max_u32(u32 v) {
  v = umax32(v, (u32)__builtin_amdgcn_update_dpp(0, (int)v, 0x111, 0xf, 0xf, false));
  v = umax32(v, (u32)__builtin_amdgcn_update_dpp(0, (int)v, 0x112, 0xf, 0xf, false));
  v = umax32(v, (u32)__builtin_amdgcn_update_dpp(0, (int)v, 0x114, 0xf, 0xf, false));
  v = umax32(v, (u32)__builtin_amdgcn_update_dpp(0, (int)v, 0x118, 0xf, 0xf, false));
  v = umax32(v, (u32)__builtin_amdgcn_update_dpp(0, (int)v, 0x142, 0xa, 0xf, false));
  v = umax32(v, (u32)__builtin_amdgcn_update_dpp(0, (int)v, 0x143, 0xc, 0xf, false));
  return (u32)__builtin_amdgcn_readlane((int)v, 63);
}
// two-phase DPP reduce == lexicographic u64 max over the wave (tie -> min idx)
__device__ inline u64 wave_max_key(u64 lkey) {
  u32 hi = (u32)(lkey >> 32), lo32v = (u32)lkey;
  u32 m = wave_max_u32(hi);
  u32 c = wave_max_u32(hi == m ? lo32v : 0u);
  return ((u64)m << 32) | c;
}

__device__ inline u32 part1by2(u32 x) {   // spread 10 bits -> every 3rd bit
  x &= 0x3ffu;
  x = (x | (x << 16)) & 0x030000FFu;
  x = (x | (x << 8))  & 0x0300F00Fu;
  x = (x | (x << 4))  & 0x030C30C3u;
  x = (x | (x << 2))  & 0x09249249u;
  return x;
}

// ---------------------------------------------------------------------------
// Kernel 1: FPS = R8 EXACT REVERT (measured 1322 us, absmax 0.0): 1024 thr,
// 8 Morton-contiguous pts/thread in registers, LDS coord table (128 KB),
// bbox prune, DPP wave argmax, single-slot triple-buffered atomicMax combine.
// R9's 512-thr experiment REGRESSED (+48%): fewer waves/SIMD halves latency
// hiding of the 2 dependent LDS reads on the serial chain, and bigger
// per-wave spatial extent kills the whole-wave ballot skip. 16 waves is the
// sweet spot. Only delta vs R8: slot-zeroing moved to t==64 (wave 1) to take
// one LDS op off wave 0's posting chain (barrier-protected, order-free).
// Key = d2bits<<32 | ~origidx -> np.argmax tie semantics.
// ---------------------------------------------------------------------------
__global__ __launch_bounds__(1024) void fps_kernel(
    const float* __restrict__ pos, int* __restrict__ samp,
    float* __restrict__ out) {
  // [0,128K): float4 tab[8192]  (overlaps u64 sortb[8192] in [0,64K) -- sortb
  //           dead before tab is written)
  // [128K, 128K+24): u64 slot[3] triple-buffered atomicMax slots
  // [128K+32, 128K+32+8K): int s_samp[2048]
  __shared__ __align__(16) unsigned char smem_raw[NPB * 16 + 32 + MS * 4];
  u64* sortb = (u64*)smem_raw;
  float4* tab = (float4*)smem_raw;
  u64* slot = (u64*)(smem_raw + NPB * 16);
  int* s_samp = (int*)(smem_raw + NPB * 16 + 32);

  int b = blockIdx.x, t = threadIdx.x, lane = t & 63;
  const float* pb = pos + (size_t)b * NPB * 3;

  // ---- 1) Morton keys (30b) | orig idx (13b) ----
  for (int i = t; i < NPB; i += 1024) {
    float xx = pb[i * 3], yy = pb[i * 3 + 1], zz = pb[i * 3 + 2];
    u32 xi = (u32)fminf(fmaxf(xx * 1024.0f, 0.0f), 1023.0f);
    u32 yi = (u32)fminf(fmaxf(yy * 1024.0f, 0.0f), 1023.0f);
    u32 zi = (u32)fminf(fmaxf(zz * 1024.0f, 0.0f), 1023.0f);
    u32 m = (part1by2(zi) << 2) | (part1by2(yi) << 1) | part1by2(xi);
    sortb[i] = ((u64)m << 13) | (u32)i;
  }
  // ---- 2) bitonic sort 8192 ----
  for (int k = 2; k <= NPB; k <<= 1) {
    for (int j = k >> 1; j > 0; j >>= 1) {
      __syncthreads();
      for (int i = t; i < NPB; i += 1024) {
        int ix = i ^ j;
        if (ix > i) {
          u64 a = sortb[i], c = sortb[ix];
          bool up = ((i & k) == 0);
          if ((a > c) == up) { sortb[i] = c; sortb[ix] = a; }
        }
      }
    }
  }
  __syncthreads();
  // ---- 3) extract my 8-pt blob (Morton-contiguous) ----
  int oi[8];
  #pragma unroll
  for (int i = 0; i < 8; ++i) oi[i] = (int)(sortb[8 * t + i] & 0x1FFFu);
  __syncthreads();                 // sort buffer dead; tab may overwrite it

  // ---- 3.5) fill LDS coordinate table (coalesced) + init slots ----
  for (int i = t; i < NPB; i += 1024) {
    float xx = pb[i * 3], yy = pb[i * 3 + 1], zz = pb[i * 3 + 2];
    tab[i] = float4{xx, yy, zz, 0.0f};
  }
  if (t < 3) slot[t] = 0;
  if (t == 0) s_samp[0] = 0;
  __syncthreads();                 // tab complete + slots zeroed

  // ---- 4) gather coords from tab + bbox + tie-break lo words; init vs pt 0 ----
  f32x2 px[4], py[4], pz[4], mind[4];
  u32 lo[8];
  float bxl = 1e30f, bxh = -1e30f, byl = 1e30f, byh = -1e30f, bzl = 1e30f, bzh = -1e30f;
  #pragma unroll
  for (int j = 0; j < 4; ++j) {
    int iA = oi[2 * j], iB = oi[2 * j + 1];
    float4 A = tab[iA], B = tab[iB];
    px[j] = f32x2{A.x, B.x}; py[j] = f32x2{A.y, B.y}; pz[j] = f32x2{A.z, B.z};
    lo[2 * j] = ~(u32)iA; lo[2 * j + 1] = ~(u32)iB;
    bxl = fminf(bxl, fminf(A.x, B.x)); bxh = fmaxf(bxh, fmaxf(A.x, B.x));
    byl = fminf(byl, fminf(A.y, B.y)); byh = fmaxf(byh, fmaxf(A.y, B.y));
    bzl = fminf(bzl, fminf(A.z, B.z)); bzh = fmaxf(bzh, fmaxf(A.z, B.z));
  }
  u64 lkey = 0, wkey;
  {
    float4 c0 = tab[0];
    f32x2 mcx = f32x2{-c0.x, -c0.x}, mcy = f32x2{-c0.y, -c0.y}, mcz = f32x2{-c0.z, -c0.z};
    #pragma unroll
    for (int j = 0; j < 4; ++j) {
      f32x2 dx = pk_add(px[j], mcx), dy = pk_add(py[j], mcy), dz = pk_add(pz[j], mcz);
      mind[j] = pk_add(pk_add(pk_mul(dx, dx), pk_mul(dy, dy)), pk_mul(dz, dz));
      u64 kA = ((u64)__float_as_uint(mind[j].x) << 32) | lo[2 * j];
      u64 kB = ((u64)__float_as_uint(mind[j].y) << 32) | lo[2 * j + 1];
      lkey = umax64(lkey, umax64(kA, kB));
    }
    wkey = wave_max_key(lkey);
  }

  // ---- 5) sequential loop: ONE barrier/iter, R5-proven slot rotation ----
  int cur = 0, nxt = 1;
  for (int it = 1; it < MS; ++it) {
    if (lane == 0) atomicMax((u64*)&slot[cur], wkey);
    if (t == 64) slot[nxt] = 0;    // wave 1 zeroes cur_{it+1}; 2 barriers before reuse
    __syncthreads();
    u64 g = slot[cur];             // broadcast read (same addr, no conflict)
    int win = (int)(~(u32)g) & (NPB - 1);
    if (t == 0) s_samp[it] = win;
    // winner coords: ONE ds_read_b128, same-address broadcast (conflict-free)
    float4 wc = tab[win];
    float ncx = wc.x, ncy = wc.y, ncz = wc.z;
    // conservative bbox skip test (bit-exact: only skips provable no-ops)
    float lmax = __uint_as_float((u32)(lkey >> 32));
    float ax = fmaxf(fmaxf(__fsub_rn(bxl, ncx), __fsub_rn(ncx, bxh)), 0.0f);
    float ay = fmaxf(fmaxf(__fsub_rn(byl, ncy), __fsub_rn(ncy, byh)), 0.0f);
    float az = fmaxf(fmaxf(__fsub_rn(bzl, ncz), __fsub_rn(ncz, bzh)), 0.0f);
    float lb2 = (ax * ax + ay * ay + az * az) * 0.9999961853f;  // *(1-2^-18)
    bool upd = (lb2 <= lmax);
    if (__ballot(upd)) {           // wave-uniform branch
      if (upd) {
        f32x2 mcx = f32x2{-ncx, -ncx}, mcy = f32x2{-ncy, -ncy}, mcz = f32x2{-ncz, -ncz};
        u64 acc = 0;
        #pragma unroll
        for (int j = 0; j < 4; ++j) {
          f32x2 dx = pk_add(px[j], mcx), dy = pk_add(py[j], mcy), dz = pk_add(pz[j], mcz);
          f32x2 d2 = pk_add(pk_add(pk_mul(dx, dx), pk_mul(dy, dy)), pk_mul(dz, dz));
          mind[j].x = fminf(mind[j].x, d2.x);
          mind[j].y = fminf(mind[j].y, d2.y);
          u64 kA = ((u64)__float_as_uint(mind[j].x) << 32) | lo[2 * j];
          u64 kB = ((u64)__float_as_uint(mind[j].y) << 32) | lo[2 * j + 1];
          acc = umax64(acc, umax64(kA, kB));
        }
        lkey = acc;
      }
      wkey = wave_max_key(lkey);   // all lanes participate (DPP)
    }
    cur = nxt;
    nxt = nxt + 1 == 3 ? 0 : nxt + 1;
  }
  __syncthreads();
  // ---- 6) writeback (coords from LDS table) ----
  float* pos_out = out + OFF_POS + (size_t)b * MS * 3;
  float* batch_out = out + OFF_BATCH + (size_t)b * MS;
  for (int m = t; m < MS; m += 1024) {
    int s = s_samp[m];
    samp[b * MS + m] = s;
    float4 c = tab[s];
    pos_out[m * 3] = c.x;
    pos_out[m * 3 + 1] = c.y;
    pos_out[m * 3 + 2] = c.z;
    batch_out[m] = (float)b;
  }
}

// ---------------------------------------------------------------------------
// Kernel 2: FUSED radius-ball/top-K + MLP. Phase 1 is the FROZEN nbr logic
// (identical instructions) but the candidate list stays in LDS -- no global
// nbr[] round-trip, no second dispatch, no inter-kernel global barrier.
// Phase 2 is the FROZEN mlp logic with nb[r] replaced by the identical
// extraction (r<n ? cand[r]&0xffffffff : -1) that nbr_kernel used to write.
// Bit-exact by construction (absmax 0.0 expected).
// LDS: 4KB cand + ~52.5KB mlp buffers = 56.3KB -> 2 blocks/CU (same as mlp).
// ---------------------------------------------------------------------------
__global__ __launch_bounds__(256) void nbr_mlp_kernel(
    const float* __restrict__ x, const float* __restrict__ pos,
    const int* __restrict__ samp,
    const float* __restrict__ W1, const float* __restrict__ b1,
    const float* __restrict__ W2, const float* __restrict__ b2,
    const float* __restrict__ W3, const float* __restrict__ b3,
    float* __restrict__ out) {
  const float R2CUT = (float)(0.2 * 0.2);   // 0x3D23D70A
  int c = blockIdx.x, b = c >> 11, t = threadIdx.x;

  __shared__ u64 cand[512];
  __shared__ int cnt;
  __shared__ float s_feat[64][68];
  __shared__ float s_h[64][68];
  __shared__ float s_w[68][64];
  __shared__ float s_mask[64];
  __shared__ float s_red[4][64];

  // ================= Phase 1: radius ball + K-nearest-in-ball ==============
  const float* pb = pos + (size_t)b * NPB * 3;
  int s = samp[c] & (NPB - 1);
  float cx = pb[s * 3], cy = pb[s * 3 + 1], cz = pb[s * 3 + 2];
  if (t == 0) cnt = 0;
  __syncthreads();
  for (int j = t; j < NPB; j += 256) {
    float dx = __fsub_rn(pb[j * 3], cx);
    float dy = __fsub_rn(pb[j * 3 + 1], cy);
    float dz = __fsub_rn(pb[j * 3 + 2], cz);
    float d2 = __fadd_rn(__fadd_rn(__fmul_rn(dx, dx), __fmul_rn(dy, dy)), __fmul_rn(dz, dz));
    if (d2 <= R2CUT) {
      int sl = atomicAdd(&cnt, 1);
      if (sl < 512) cand[sl] = ((u64)__float_as_uint(d2) << 32) | (u32)j;
    }
  }
  __syncthreads();
  int n = cnt; if (n > 512) n = 512;
  for (int i = t; i < 512; i += 256) if (i >= n) cand[i] = ~0ull;
  __syncthreads();
  for (int k = 2; k <= 512; k <<= 1) {
    for (int j = k >> 1; j > 0; j >>= 1) {
      for (int i = t; i < 512; i += 256) {
        int ix = i ^ j;
        if (ix > i) {
          u64 a = cand[i], bb = cand[ix];
          bool up = ((i & k) == 0);
          if ((a > bb) == up) { cand[i] = bb; cand[ix] = a; }
        }
      }
      __syncthreads();
    }
  }
  // cand[0..63] sorted; neighbor r = (r<n) ? (int)(cand[r]&0xffffffff) : -1

  // ================= Phase 2: gather -> MLP -> masked max-pool =============
  {
    int r = t >> 2, q = t & 3;
    int j = (r < n) ? (int)(cand[r] & 0xffffffffu) : -1;
    bool valid = (j >= 0 && j < NPB);
    size_t jj = valid ? (size_t)j : 0;
    const float4* xp = (const float4*)(x + ((size_t)b * NPB + jj) * 64 + q * 16);
    float4 v[4];
    for (int i = 0; i < 4; ++i) v[i] = xp[i];
    for (int i = 0; i < 4; ++i) {
      s_feat[r][q * 16 + i * 4 + 0] = valid ? v[i].x : 0.0f;
      s_feat[r][q * 16 + i * 4 + 1] = valid ? v[i].y : 0.0f;
      s_feat[r][q * 16 + i * 4 + 2] = valid ? v[i].z : 0.0f;
      s_feat[r][q * 16 + i * 4 + 3] = valid ? v[i].w : 0.0f;
    }
  }
  if (t < 64) {
    int r = t;
    int j = (r < n) ? (int)(cand[r] & 0xffffffffu) : -1;
    bool valid = (j >= 0 && j < NPB);
    s_mask[r] = valid ? 0.0f : -__builtin_inff();
    size_t jj = valid ? (size_t)j : (size_t)s;
    for (int d = 0; d < 3; ++d) {
      float pj = pos[((size_t)b * NPB + jj) * 3 + d];
      float pc = pos[((size_t)b * NPB + s) * 3 + d];
      s_feat[r][64 + d] = __fsub_rn(pj, pc);
    }
  }
  for (int idx = t; idx < 67 * 64; idx += 256)
    s_w[idx >> 6][idx & 63] = W1[idx];
  __syncthreads();

  {
    int r = t >> 2, n0 = (t & 3) * 16;
    float acc[16];
    for (int j = 0; j < 16; ++j) acc[j] = b1[n0 + j];
    for (int k = 0; k < 67; ++k) {
      float f = s_feat[r][k];
      for (int j = 0; j < 16; ++j) acc[j] += f * s_w[k][n0 + j];
    }
    __syncthreads();
    for (int j = 0; j < 16; ++j) s_h[r][n0 + j] = fmaxf(acc[j], 0.0f);
  }
  for (int idx = t; idx < 64 * 64; idx += 256)
    s_w[idx >> 6][idx & 63] = W2[idx];
  __syncthreads();

  {
    int r = t >> 2, n0 = (t & 3) * 16;
    float acc[16];
    for (int j = 0; j < 16; ++j) acc[j] = b2[n0 + j];
    for (int k = 0; k < 64; ++k) {
      float f = s_h[r][k];
      for (int j = 0; j < 16; ++j) acc[j] += f * s_w[k][n0 + j];
    }
    __syncthreads();
    for (int j = 0; j < 16; ++j) s_feat[r][n0 + j] = fmaxf(acc[j], 0.0f);
  }
  __syncthreads();

  for (int h = 0; h < 2; ++h) {
    for (int idx = t; idx < 64 * 64; idx += 256)
      s_w[idx >> 6][idx & 63] = W3[(size_t)(idx >> 6) * 128 + h * 64 + (idx & 63)];
    __syncthreads();
    int n2 = t & 63, rg = t >> 6;
    float acc[16];
    float bias = b3[h * 64 + n2];
    for (int rr = 0; rr < 16; ++rr) acc[rr] = bias;
    for (int k = 0; k < 64; ++k) {
      float w = s_w[k][n2];
      for (int rr = 0; rr < 16; ++rr) acc[rr] += s_feat[rg * 16 + rr][k] * w;
    }
    float m = -__builtin_inff();
    for (int rr = 0; rr < 16; ++rr)
      m = fmaxf(m, fmaxf(acc[rr], 0.0f) + s_mask[rg * 16 + rr]);
    s_red[rg][n2] = m;
    __syncthreads();
    if (t < 64) {
      float mm = fmaxf(fmaxf(s_red[0][t], s_red[1][t]), fmaxf(s_red[2][t], s_red[3][t]));
      out[(size_t)c * 128 + h * 64 + t] = mm;
    }
    __syncthreads();
  }
}

// ---------------------------------------------------------------------------
extern "C" void kernel_launch(void* const* d_in, const int* in_sizes, int n_in,
                              void* d_out, int out_size, void* d_ws, size_t ws_size,
                              hipStream_t stream) {
  const float* x   = (const float*)d_in[0];
  const float* pos = (const float*)d_in[1];
  // d_in[2] = batch (int32), unused
  const float* W1 = (const float*)d_in[3];
  const float* b1 = (const float*)d_in[4];
  const float* W2 = (const float*)d_in[5];
  const float* b2 = (const float*)d_in[6];
  const float* W3 = (const float*)d_in[7];
  const float* b3 = (const float*)d_in[8];

  float* out = (float*)d_out;
  int* samp = (int*)d_ws;            // [8192]

  fps_kernel<<<BCL, 1024, 0, stream>>>(pos, samp, out);
  nbr_mlp_kernel<<<BCL * MS, 256, 0, stream>>>(x, pos, samp,
                                               W1, b1, W2, b2, W3, b3, out);
}

// Round 4
// 1443.377 us; speedup vs baseline: 1.7576x; 1.4986x over previous
//
#include <hip/hip_runtime.h>

typedef unsigned int u32;
typedef unsigned long long u64;
typedef float f32x2 __attribute__((ext_vector_type(2)));

#define NPB 8192
#define BCL 4
#define MS 2048
#define KN 64
#define OFF_POS   (BCL * MS * 128)            // element offsets into d_out (f32)
#define OFF_BATCH (OFF_POS + BCL * MS * 3)
#define SMEM_BYTES (NPB * 16 + 32 + MS * 4)   // 139296: fps layout (union max)

__device__ inline u64 umax64(u64 a, u64 b) { return a < b ? b : a; }
__device__ inline u32 umax32(u32 a, u32 b) { return a < b ? b : a; }

// packed f32 ops: IEEE-identical per half to v_add_f32 / v_mul_f32 -> bit-exact
__device__ inline f32x2 pk_add(f32x2 a, f32x2 b) {
  f32x2 d;
  asm("v_pk_add_f32 %0, %1, %2" : "=v"(d) : "v"(a), "v"(b));
  return d;
}
__device__ inline f32x2 pk_mul(f32x2 a, f32x2 b) {
  f32x2 d;
  asm("v_pk_mul_f32 %0, %1, %2" : "=v"(d) : "v"(a), "v"(b));
  return d;
}

// wave64 max via DPP (VALU forwarding, no LDS round-trips).
__device__ inline u32 wave_max_u32(u32 v) {
  v = umax32(v, (u32)__builtin_amdgcn_update_dpp(0, (int)v, 0x111, 0xf, 0xf, false));
  v = umax32(v, (u32)__builtin_amdgcn_update_dpp(0, (int)v, 0x112, 0xf, 0xf, false));
  v = umax32(v, (u32)__builtin_amdgcn_update_dpp(0, (int)v, 0x114, 0xf, 0xf, false));
  v = umax32(v, (u32)__builtin_amdgcn_update_dpp(0, (int)v, 0x118, 0xf, 0xf, false));
  v = umax32(v, (u32)__builtin_amdgcn_update_dpp(0, (int)v, 0x142, 0xa, 0xf, false));
  v = umax32(v, (u32)__builtin_amdgcn_update_dpp(0, (int)v, 0x143, 0xc, 0xf, false));
  return (u32)__builtin_amdgcn_readlane((int)v, 63);
}
// two-phase DPP reduce == lexicographic u64 max over the wave (tie -> min idx)
__device__ inline u64 wave_max_key(u64 lkey) {
  u32 hi = (u32)(lkey >> 32), lo32v = (u32)lkey;
  u32 m = wave_max_u32(hi);
  u32 c = wave_max_u32(hi == m ? lo32v : 0u);
  return ((u64)m << 32) | c;
}

__device__ inline u32 part1by2(u32 x) {   // spread 10 bits -> every 3rd bit
  x &= 0x3ffu;
  x = (x | (x << 16)) & 0x030000FFu;
  x = (x | (x << 8))  & 0x0300F00Fu;
  x = (x | (x << 4))  & 0x030C30C3u;
  x = (x | (x << 2))  & 0x09249249u;
  return x;
}

// Zero the ready flags each launch (graph-replay safe; stream-ordered).
__global__ __launch_bounds__(1024) void init_ready(u32* __restrict__ ready) {
  int i = blockIdx.x * 1024 + threadIdx.x;
  if (i < BCL * MS) ready[i] = 0u;
}

// ---------------------------------------------------------------------------
// PIPELINE kernel: blocks 0..3 = FPS producer (R8/R3 structure, 1317 us
// proven, absmax 0.0). Blocks 4.. = per-center consumer (radius scan ->
// bitonic top-K -> MLP -> masked max-pool), spin-waiting on a device-scope
// atomic ready flag that carries the sample value (win+1). Consumers ride
// under fps's 1317-us shadow: production 6.2 centers/us, consumer capacity
// ~20/us on 252 CUs -> total ~= fps + drain.
//  - samples travel INSIDE atomics (device-scope, cross-XCD coherent);
//  - inputs read-only; output regions disjoint;
//  - consumer MLP re-partitioned to 1024 thr: each output element computed by
//    exactly one thread with the identical sequential-k FMA chain -> bit-exact;
//    max-pool is exact max (order-free); cand cap 1024 >= any physical ball
//    population -> capture order irrelevant.
// ---------------------------------------------------------------------------
__global__ __launch_bounds__(1024) void pipeline_kernel(
    const float* __restrict__ x, const float* __restrict__ pos,
    u32* __restrict__ ready,
    const float* __restrict__ W1, const float* __restrict__ b1,
    const float* __restrict__ W2, const float* __restrict__ b2,
    const float* __restrict__ W3, const float* __restrict__ b3,
    float* __restrict__ out) {
  __shared__ __align__(16) unsigned char smem_raw[SMEM_BYTES];
  int t = threadIdx.x;

  if (blockIdx.x < BCL) {
    // =================== FPS producer (R3-proven body) =====================
    u64* sortb = (u64*)smem_raw;
    float4* tab = (float4*)smem_raw;
    u64* slot = (u64*)(smem_raw + NPB * 16);
    int* s_samp = (int*)(smem_raw + NPB * 16 + 32);

    int b = blockIdx.x, lane = t & 63;
    const float* pb = pos + (size_t)b * NPB * 3;

    // sample 0 is always point 0: post immediately so consumers start now
    if (t == 1) atomicExch(&ready[(size_t)b * MS], 1u);

    // ---- 1) Morton keys (30b) | orig idx (13b) ----
    for (int i = t; i < NPB; i += 1024) {
      float xx = pb[i * 3], yy = pb[i * 3 + 1], zz = pb[i * 3 + 2];
      u32 xi = (u32)fminf(fmaxf(xx * 1024.0f, 0.0f), 1023.0f);
      u32 yi = (u32)fminf(fmaxf(yy * 1024.0f, 0.0f), 1023.0f);
      u32 zi = (u32)fminf(fmaxf(zz * 1024.0f, 0.0f), 1023.0f);
      u32 m = (part1by2(zi) << 2) | (part1by2(yi) << 1) | part1by2(xi);
      sortb[i] = ((u64)m << 13) | (u32)i;
    }
    // ---- 2) bitonic sort 8192 ----
    for (int k = 2; k <= NPB; k <<= 1) {
      for (int j = k >> 1; j > 0; j >>= 1) {
        __syncthreads();
        for (int i = t; i < NPB; i += 1024) {
          int ix = i ^ j;
          if (ix > i) {
            u64 a = sortb[i], c = sortb[ix];
            bool up = ((i & k) == 0);
            if ((a > c) == up) { sortb[i] = c; sortb[ix] = a; }
          }
        }
      }
    }
    __syncthreads();
    // ---- 3) extract my 8-pt blob (Morton-contiguous) ----
    int oi[8];
    #pragma unroll
    for (int i = 0; i < 8; ++i) oi[i] = (int)(sortb[8 * t + i] & 0x1FFFu);
    __syncthreads();               // sort buffer dead; tab may overwrite it

    // ---- 3.5) fill LDS coordinate table (coalesced) + init slots ----
    for (int i = t; i < NPB; i += 1024) {
      float xx = pb[i * 3], yy = pb[i * 3 + 1], zz = pb[i * 3 + 2];
      tab[i] = float4{xx, yy, zz, 0.0f};
    }
    if (t < 3) slot[t] = 0;
    if (t == 0) s_samp[0] = 0;
    __syncthreads();               // tab complete + slots zeroed

    // ---- 4) gather coords + bbox + tie-break lo words; init vs point 0 ----
    f32x2 px[4], py[4], pz[4], mind[4];
    u32 lo[8];
    float bxl = 1e30f, bxh = -1e30f, byl = 1e30f, byh = -1e30f, bzl = 1e30f, bzh = -1e30f;
    #pragma unroll
    for (int j = 0; j < 4; ++j) {
      int iA = oi[2 * j], iB = oi[2 * j + 1];
      float4 A = tab[iA], B = tab[iB];
      px[j] = f32x2{A.x, B.x}; py[j] = f32x2{A.y, B.y}; pz[j] = f32x2{A.z, B.z};
      lo[2 * j] = ~(u32)iA; lo[2 * j + 1] = ~(u32)iB;
      bxl = fminf(bxl, fminf(A.x, B.x)); bxh = fmaxf(bxh, fmaxf(A.x, B.x));
      byl = fminf(byl, fminf(A.y, B.y)); byh = fmaxf(byh, fmaxf(A.y, B.y));
      bzl = fminf(bzl, fminf(A.z, B.z)); bzh = fmaxf(bzh, fmaxf(A.z, B.z));
    }
    u64 lkey = 0, wkey;
    {
      float4 c0 = tab[0];
      f32x2 mcx = f32x2{-c0.x, -c0.x}, mcy = f32x2{-c0.y, -c0.y}, mcz = f32x2{-c0.z, -c0.z};
      #pragma unroll
      for (int j = 0; j < 4; ++j) {
        f32x2 dx = pk_add(px[j], mcx), dy = pk_add(py[j], mcy), dz = pk_add(pz[j], mcz);
        mind[j] = pk_add(pk_add(pk_mul(dx, dx), pk_mul(dy, dy)), pk_mul(dz, dz));
        u64 kA = ((u64)__float_as_uint(mind[j].x) << 32) | lo[2 * j];
        u64 kB = ((u64)__float_as_uint(mind[j].y) << 32) | lo[2 * j + 1];
        lkey = umax64(lkey, umax64(kA, kB));
      }
      wkey = wave_max_key(lkey);
    }

    // ---- 5) sequential loop: ONE barrier/iter ----
    int cur = 0, nxt = 1;
    for (int it = 1; it < MS; ++it) {
      if (lane == 0) atomicMax((u64*)&slot[cur], wkey);
      if (t == 64) slot[nxt] = 0;  // wave 1 zeroes cur_{it+1}
      __syncthreads();
      u64 g = slot[cur];           // broadcast read (same addr, no conflict)
      int win = (int)(~(u32)g) & (NPB - 1);
      if (t == 0) s_samp[it] = win;
      // post the sample to consumers: fire-and-forget device-scope atomic,
      // issued ~1 iteration before this wave's next vmcnt-drain -> off chain
      if (t == 65) atomicExch(&ready[(size_t)b * MS + it], (u32)(win + 1));
      // winner coords: ONE ds_read_b128, same-address broadcast
      float4 wc = tab[win];
      float ncx = wc.x, ncy = wc.y, ncz = wc.z;
      // conservative bbox skip test (bit-exact: only skips provable no-ops)
      float lmax = __uint_as_float((u32)(lkey >> 32));
      float ax = fmaxf(fmaxf(__fsub_rn(bxl, ncx), __fsub_rn(ncx, bxh)), 0.0f);
      float ay = fmaxf(fmaxf(__fsub_rn(byl, ncy), __fsub_rn(ncy, byh)), 0.0f);
      float az = fmaxf(fmaxf(__fsub_rn(bzl, ncz), __fsub_rn(ncz, bzh)), 0.0f);
      float lb2 = (ax * ax + ay * ay + az * az) * 0.9999961853f;  // *(1-2^-18)
      bool upd = (lb2 <= lmax);
      if (__ballot(upd)) {         // wave-uniform branch
        if (upd) {
          f32x2 mcx = f32x2{-ncx, -ncx}, mcy = f32x2{-ncy, -ncy}, mcz = f32x2{-ncz, -ncz};
          u64 acc = 0;
          #pragma unroll
          for (int j = 0; j < 4; ++j) {
            f32x2 dx = pk_add(px[j], mcx), dy = pk_add(py[j], mcy), dz = pk_add(pz[j], mcz);
            f32x2 d2 = pk_add(pk_add(pk_mul(dx, dx), pk_mul(dy, dy)), pk_mul(dz, dz));
            mind[j].x = fminf(mind[j].x, d2.x);
            mind[j].y = fminf(mind[j].y, d2.y);
            u64 kA = ((u64)__float_as_uint(mind[j].x) << 32) | lo[2 * j];
            u64 kB = ((u64)__float_as_uint(mind[j].y) << 32) | lo[2 * j + 1];
            acc = umax64(acc, umax64(kA, kB));
          }
          lkey = acc;
        }
        wkey = wave_max_key(lkey); // all lanes participate (DPP)
      }
      cur = nxt;
      nxt = nxt + 1 == 3 ? 0 : nxt + 1;
    }
    __syncthreads();
    // ---- 6) writeback (coords from LDS table) ----
    float* pos_out = out + OFF_POS + (size_t)b * MS * 3;
    float* batch_out = out + OFF_BATCH + (size_t)b * MS;
    for (int m = t; m < MS; m += 1024) {
      int s = s_samp[m];
      float4 c = tab[s];
      pos_out[m * 3] = c.x;
      pos_out[m * 3 + 1] = c.y;
      pos_out[m * 3 + 2] = c.z;
      batch_out[m] = (float)b;
    }
    return;
  }

  // ===================== Consumer: one center per block =====================
  // cloud-interleaved assignment matches production order across the 4 fps
  // blocks: cblk = {b = cblk&3, m = cblk>>2}
  {
    int cblk = blockIdx.x - BCL;
    int b = cblk & (BCL - 1), m = cblk >> 2;
    int c = b * MS + m;               // global center id (output index)
    const float R2CUT = (float)(0.2 * 0.2);   // 0x3D23D70A

    // LDS carve (union with fps layout; 64784 B total)
    u64* cand = (u64*)smem_raw;                               // 1024 x u64
    int* s_cnt = (int*)(smem_raw + 8192);
    int* s_win = (int*)(smem_raw + 8196);
    float (*s_feat)[68] = (float(*)[68])(smem_raw + 8208);
    float (*s_h)[68]    = (float(*)[68])(smem_raw + 8208 + 17408);
    float (*s_w)[64]    = (float(*)[64])(smem_raw + 8208 + 34816);
    float* s_mask       = (float*)(smem_raw + 8208 + 52224);  // 64 floats
    float (*s_red)[64]  = (float(*)[64])(smem_raw + 8208 + 52480); // [16][64]

    const float* pb = pos + (size_t)b * NPB * 3;

    // ---- spin until our sample is produced (value travels in the atomic) --
    if (t == 0) {
      u32 v;
      while ((v = atomicAdd(&ready[c], 0u)) == 0u) __builtin_amdgcn_s_sleep(8);
      *s_win = (int)(v - 1u);
      *s_cnt = 0;
    }
    __syncthreads();
    int s = *s_win;
    float cx = pb[s * 3], cy = pb[s * 3 + 1], cz = pb[s * 3 + 2];

    // ---- Phase 1: radius scan (1024 thr; order-free, cap >= ball pop) ----
    for (int j = t; j < NPB; j += 1024) {
      float dx = __fsub_rn(pb[j * 3], cx);
      float dy = __fsub_rn(pb[j * 3 + 1], cy);
      float dz = __fsub_rn(pb[j * 3 + 2], cz);
      float d2 = __fadd_rn(__fadd_rn(__fmul_rn(dx, dx), __fmul_rn(dy, dy)), __fmul_rn(dz, dz));
      if (d2 <= R2CUT) {
        int sl = atomicAdd(s_cnt, 1);
        if (sl < 1024) cand[sl] = ((u64)__float_as_uint(d2) << 32) | (u32)j;
      }
    }
    __syncthreads();
    int n = *s_cnt; if (n > 1024) n = 1024;
    if (t >= n) cand[t] = ~0ull;
    __syncthreads();
    // bitonic sort 1024 (one element per thread); ascending (d2, idx)
    for (int k = 2; k <= 1024; k <<= 1) {
      for (int j = k >> 1; j > 0; j >>= 1) {
        int ix = t ^ j;
        if (ix > t) {
          u64 a = cand[t], bb = cand[ix];
          bool up = ((t & k) == 0);
          if ((a > bb) == up) { cand[t] = bb; cand[ix] = a; }
        }
        __syncthreads();
      }
    }
    // cand[0..63] = top-K; neighbor r = (r<n) ? (int)(cand[r]&0xffffffff) : -1

    // ---- Phase 2: gather (1024 thr: one float4 per thread) ----
    {
      int r = t >> 4, qq = t & 15;
      int j = (r < n) ? (int)(cand[r] & 0xffffffffu) : -1;
      bool valid = (j >= 0 && j < NPB);
      size_t jj = valid ? (size_t)j : 0;
      float4 v = ((const float4*)(x + ((size_t)b * NPB + jj) * 64))[qq];
      s_feat[r][qq * 4 + 0] = valid ? v.x : 0.0f;
      s_feat[r][qq * 4 + 1] = valid ? v.y : 0.0f;
      s_feat[r][qq * 4 + 2] = valid ? v.z : 0.0f;
      s_feat[r][qq * 4 + 3] = valid ? v.w : 0.0f;
    }
    if (t < 64) {
      int r = t;
      int j = (r < n) ? (int)(cand[r] & 0xffffffffu) : -1;
      bool valid = (j >= 0 && j < NPB);
      s_mask[r] = valid ? 0.0f : -__builtin_inff();
      size_t jj = valid ? (size_t)j : (size_t)s;
      for (int d = 0; d < 3; ++d) {
        float pj = pos[((size_t)b * NPB + jj) * 3 + d];
        float pc = pos[((size_t)b * NPB + s) * 3 + d];
        s_feat[r][64 + d] = __fsub_rn(pj, pc);
      }
    }
    for (int idx = t; idx < 67 * 64; idx += 1024)
      s_w[idx >> 6][idx & 63] = W1[idx];
    __syncthreads();

    // ---- Layer 1: 64x67 @ 67x64 (each thread: 4 outputs, same k-order) ----
    {
      int r = t >> 4, n0 = (t & 15) * 4;
      float acc[4];
      for (int j = 0; j < 4; ++j) acc[j] = b1[n0 + j];
      for (int k = 0; k < 67; ++k) {
        float f = s_feat[r][k];
        for (int j = 0; j < 4; ++j) acc[j] += f * s_w[k][n0 + j];
      }
      __syncthreads();
      for (int j = 0; j < 4; ++j) s_h[r][n0 + j] = fmaxf(acc[j], 0.0f);
    }
    for (int idx = t; idx < 64 * 64; idx += 1024)
      s_w[idx >> 6][idx & 63] = W2[idx];
    __syncthreads();

    // ---- Layer 2 ----
    {
      int r = t >> 4, n0 = (t & 15) * 4;
      float acc[4];
      for (int j = 0; j < 4; ++j) acc[j] = b2[n0 + j];
      for (int k = 0; k < 64; ++k) {
        float f = s_h[r][k];
        for (int j = 0; j < 4; ++j) acc[j] += f * s_w[k][n0 + j];
      }
      __syncthreads();
      for (int j = 0; j < 4; ++j) s_feat[r][n0 + j] = fmaxf(acc[j], 0.0f);
    }
    __syncthreads();

    // ---- Layer 3 (2 halves of 128) + masked max-pool ----
    for (int h = 0; h < 2; ++h) {
      for (int idx = t; idx < 64 * 64; idx += 1024)
        s_w[idx >> 6][idx & 63] = W3[(size_t)(idx >> 6) * 128 + h * 64 + (idx & 63)];
      __syncthreads();
      int n2 = t & 63, rg = t >> 6;    // rg in [0,16): 4 rows each
      float acc[4];
      float bias = b3[h * 64 + n2];
      for (int rr = 0; rr < 4; ++rr) acc[rr] = bias;
      for (int k = 0; k < 64; ++k) {
        float w = s_w[k][n2];
        for (int rr = 0; rr < 4; ++rr) acc[rr] += s_feat[rg * 4 + rr][k] * w;
      }
      float mm = -__builtin_inff();
      for (int rr = 0; rr < 4; ++rr)
        mm = fmaxf(mm, fmaxf(acc[rr], 0.0f) + s_mask[rg * 4 + rr]);
      s_red[rg][n2] = mm;
      __syncthreads();
      if (t < 64) {
        float m0 = s_red[0][t];
        for (int g2 = 1; g2 < 16; ++g2) m0 = fmaxf(m0, s_red[g2][t]);
        out[(size_t)c * 128 + h * 64 + t] = m0;
      }
      __syncthreads();
    }
  }
}

// ---------------------------------------------------------------------------
extern "C" void kernel_launch(void* const* d_in, const int* in_sizes, int n_in,
                              void* d_out, int out_size, void* d_ws, size_t ws_size,
                              hipStream_t stream) {
  const float* x   = (const float*)d_in[0];
  const float* pos = (const float*)d_in[1];
  // d_in[2] = batch (int32), unused
  const float* W1 = (const float*)d_in[3];
  const float* b1 = (const float*)d_in[4];
  const float* W2 = (const float*)d_in[5];
  const float* b2 = (const float*)d_in[6];
  const float* W3 = (const float*)d_in[7];
  const float* b3 = (const float*)d_in[8];

  float* out = (float*)d_out;
  u32* ready = (u32*)d_ws;           // [8192] sample-ready flags (win+1)

  init_ready<<<(BCL * MS + 1023) / 1024, 1024, 0, stream>>>(ready);
  pipeline_kernel<<<BCL + BCL * MS, 1024, 0, stream>>>(
      x, pos, ready, W1, b1, W2, b2, W3, b3, out);
}